// Round 4
// baseline (257.647 us; speedup 1.0000x reference)
//
#include <hip/hip_runtime.h>
#include <hip/hip_bf16.h>
#include <cstdint>

#define N_TOK 4096
#define KTOP  64
#define DIM   1024
#define NLAT  16384
#define NCHUNK 8      // 128 cols/chunk -> 4 MB bf16 per chunk == one XCD L2

typedef __bf16 bf16x8 __attribute__((ext_vector_type(8)));
typedef float  floatx4 __attribute__((ext_vector_type(4)));
typedef float  f32x4   __attribute__((ext_vector_type(4)));
typedef unsigned int   u32x2   __attribute__((ext_vector_type(2)));
typedef unsigned short ushortx8 __attribute__((ext_vector_type(8)));

#define GLOBAL_AS(p) ((const __attribute__((address_space(1))) void*)(p))
#define LDS_AS(p)    ((__attribute__((address_space(3))) void*)(p))

__device__ inline unsigned short f2bf(float f){
  unsigned int u = __float_as_uint(f);
  unsigned int r = (u + 0x7fffu + ((u >> 16) & 1u)) >> 16;  // RNE
  return (unsigned short)r;
}
__device__ inline float bflo(unsigned int u){ return __uint_as_float(u << 16); }
__device__ inline float bfhi(unsigned int u){ return __uint_as_float(u & 0xffff0000u); }

// read 8 consecutive f32 (2x float4), write one 16B ushort8 bf16 store
__device__ inline void cvt8(const float* __restrict__ src, unsigned short* __restrict__ dst){
  float4 a = ((const float4*)src)[0];
  float4 b = ((const float4*)src)[1];
  ushortx8 o;
  o[0] = f2bf(a.x); o[1] = f2bf(a.y); o[2] = f2bf(a.z); o[3] = f2bf(a.w);
  o[4] = f2bf(b.x); o[5] = f2bf(b.y); o[6] = f2bf(b.z); o[7] = f2bf(b.w);
  *(ushortx8*)dst = o;
}

// Roles (ystats FIRST so its slightly-larger blocks launch at t=0):
//   [0,256)      ystats: colsum + sum(y^2), 16 rows/block, relaxed atomics
//   [256,1280)   x->bf16
//   [1280,1536)  Wskip->bf16
//   [1536,5632)  Wdec->chunked bf16
//   [5632,5696)  act precompute
// accs zeroed by hipMemsetAsync BEFORE this kernel (ystats atomics need it).
__global__ __launch_bounds__(256) void prep(
    const float* __restrict__ x, const float* __restrict__ Wsk,
    const float* __restrict__ Wd, const float* __restrict__ y,
    const float* __restrict__ la, const int* __restrict__ li,
    const float* __restrict__ pe, const float* __restrict__ pes,
    unsigned short* __restrict__ xb, unsigned short* __restrict__ wb,
    unsigned short* __restrict__ wdc,
    uint2* __restrict__ actbuf, float* __restrict__ accs){
  const int b = blockIdx.x;
  const int t = threadIdx.x;
  __shared__ float s_red[4];
  if (b < 256){
    const int r0 = b * 16;
    float4 cs = {0.f, 0.f, 0.f, 0.f};
    float sq = 0.f;
    for (int r = 0; r < 16; r++){
      float4 v = ((const float4*)(y + (size_t)(r0 + r) * DIM))[t];
      cs.x += v.x; cs.y += v.y; cs.z += v.z; cs.w += v.w;
      sq += v.x*v.x + v.y*v.y + v.z*v.z + v.w*v.w;
    }
    atomicAdd(&accs[4 + t*4 + 0], cs.x);
    atomicAdd(&accs[4 + t*4 + 1], cs.y);
    atomicAdd(&accs[4 + t*4 + 2], cs.z);
    atomicAdd(&accs[4 + t*4 + 3], cs.w);
    #pragma unroll
    for (int off = 32; off > 0; off >>= 1) sq += __shfl_down(sq, off, 64);
    if ((t & 63) == 0) s_red[t >> 6] = sq;
    __syncthreads();
    if (t == 0) atomicAdd(&accs[1], s_red[0] + s_red[1] + s_red[2] + s_red[3]);
  } else if (b < 1280){
    #pragma unroll
    for (int i = 0; i < 2; i++){
      int idx = (b - 256) * 4096 + i * 2048 + t * 8;
      cvt8(x + idx, xb + idx);
    }
  } else if (b < 1536){
    #pragma unroll
    for (int i = 0; i < 2; i++){
      int idx = (b - 1280) * 4096 + i * 2048 + t * 8;
      cvt8(Wsk + idx, wb + idx);
    }
  } else if (b < 5632){
    const int j = t & 127;          // 128 threads per row, 8 floats each
    const int chunk = j >> 4;
    #pragma unroll
    for (int i = 0; i < 2; i++){
      int lat = (b - 1536) * 4 + i * 2 + (t >> 7);
      cvt8(Wd + (size_t)lat * DIM + j * 8,
           wdc + ((size_t)chunk * NLAT + lat) * 128 + (j & 15) * 8);
    }
  } else {
    int e0 = (b - 5632) * 4096 + t;
    #pragma unroll
    for (int i = 0; i < 16; i++){
      int e = e0 + i * 256;
      int id = li[e];
      float a = (la[e] + pe[id]) * pes[id];
      actbuf[e] = make_uint2(__float_as_uint(a), (unsigned)id * 256u);
    }
  }
}

// 128 rows x 64 cols tile -> 512 blocks (2 blocks/CU). m97-style staging. (unchanged)
__global__ __launch_bounds__(256) void skip_gemm(
    const unsigned short* __restrict__ xb,
    const unsigned short* __restrict__ wb,
    const float* __restrict__ b_dec,
    float* __restrict__ out){
  __shared__ unsigned short As[128][32];
  __shared__ unsigned short Bs[64][32];
  const int row0 = blockIdx.x * 128;
  const int col0 = blockIdx.y * 64;
  const int t    = threadIdx.x;
  const int lane = t & 63;
  const int w    = t >> 6;
  const int wr   = w * 32;
  const int lm   = lane & 15;
  const int kq   = lane >> 4;
  const int sr   = t >> 2;
  const int sc   = (t & 3) * 8;

  floatx4 acc[2][4] = {};

  for (int k0 = 0; k0 < DIM; k0 += 32){
    __builtin_amdgcn_global_load_lds(GLOBAL_AS(xb + (size_t)(row0 + sr) * DIM + k0 + sc),
                                     LDS_AS(&As[sr][sc]), 16, 0, 0);
    __builtin_amdgcn_global_load_lds(GLOBAL_AS(xb + (size_t)(row0 + 64 + sr) * DIM + k0 + sc),
                                     LDS_AS(&As[64 + sr][sc]), 16, 0, 0);
    __builtin_amdgcn_global_load_lds(GLOBAL_AS(wb + (size_t)(col0 + sr) * DIM + k0 + sc),
                                     LDS_AS(&Bs[sr][sc]), 16, 0, 0);
    __syncthreads();
    bf16x8 af[2], bfr[4];
    #pragma unroll
    for (int mi = 0; mi < 2; mi++) af[mi] = *(const bf16x8*)(&As[wr + mi * 16 + lm][kq * 8]);
    #pragma unroll
    for (int ni = 0; ni < 4; ni++) bfr[ni] = *(const bf16x8*)(&Bs[ni * 16 + lm][kq * 8]);
    #pragma unroll
    for (int mi = 0; mi < 2; mi++)
      #pragma unroll
      for (int ni = 0; ni < 4; ni++)
        acc[mi][ni] = __builtin_amdgcn_mfma_f32_16x16x32_bf16(af[mi], bfr[ni], acc[mi][ni], 0, 0, 0);
    __syncthreads();
  }

  const int rq = (lane >> 4) * 4;   // C/D: col=lane&15, row=(lane>>4)*4+reg
  #pragma unroll
  for (int mi = 0; mi < 2; mi++){
    #pragma unroll
    for (int ni = 0; ni < 4; ni++){
      int col = col0 + ni * 16 + lm;
      float bd = b_dec[col];
      #pragma unroll
      for (int r = 0; r < 4; r++){
        int row = row0 + wr + mi * 16 + rq + r;
        out[(size_t)row * DIM + col] = acc[mi][ni][r] + bd;
      }
    }
  }
}

// Chunked decode — round-0 structure verbatim (compiler-pipelined unroll-16 loop,
// MINIMAL sse-only epilogue; the colsum epilogue of rounds 1-3 made regalloc throttle
// the gather pipeline: VGPR 60->32/48, dur 51->82+). Kept from later rounds: actbuf
// precompute (no pe/pes re-gathers) and nt streams (FETCH 84->47 MB, protects the
// 4 MB W_dec chunk's XCD-L2 residency). No fences (round-1 lesson: buffer_inv wipes L2).
__global__ __launch_bounds__(256) void decode_residual(
    const float* __restrict__ y,
    const uint2* __restrict__ actbuf,
    const unsigned short* __restrict__ Wdc,  // [NCHUNK][NLAT][128] bf16
    float* __restrict__ out,
    float* __restrict__ sse){
  const int chunk = blockIdx.x & 7;          // == XCD id under round-robin dispatch
  const int tok0  = (blockIdx.x >> 3) * 16;
  const int t  = threadIdx.x;
  const int tl = t >> 4;       // token lane 0..15
  const int cl = t & 15;       // col lane (8 cols each)
  __shared__ uint2 s_ai[16][66];   // stride 66 -> conflict-free
  __shared__ float s_red[4];

  #pragma unroll
  for (int i = 0; i < 4; i++){
    int e = t + i * 256;                 // (tok = e>>6, k = e&63)
    u32x2 v = __builtin_nontemporal_load((const u32x2*)&actbuf[tok0 * KTOP + e]);
    s_ai[e >> 6][e & 63] = make_uint2(v[0], v[1]);
  }
  __syncthreads();
  const int n = tok0 + tl;
  const char* Wbase = (const char*)Wdc + (size_t)chunk * NLAT * 256 + cl * 16;
  float* op = out + (size_t)n * DIM + chunk * 128 + cl * 8;
  const float* yp = y + (size_t)n * DIM + chunk * 128 + cl * 8;
  f32x4 o0 = __builtin_nontemporal_load((const f32x4*)op);
  f32x4 o1 = __builtin_nontemporal_load((const f32x4*)op + 1);
  f32x4 y0 = __builtin_nontemporal_load((const f32x4*)yp);
  f32x4 y1 = __builtin_nontemporal_load((const f32x4*)yp + 1);

  float acc[8] = {};
  #pragma unroll 16
  for (int k = 0; k < KTOP; k++){
    uint2 p = s_ai[tl][k];
    const float a = __uint_as_float(p.x);
    const uint4 wv = *(const uint4*)(Wbase + p.y);
    acc[0] += a * bflo(wv.x); acc[1] += a * bfhi(wv.x);
    acc[2] += a * bflo(wv.y); acc[3] += a * bfhi(wv.y);
    acc[4] += a * bflo(wv.z); acc[5] += a * bfhi(wv.z);
    acc[6] += a * bflo(wv.w); acc[7] += a * bfhi(wv.w);
  }
  acc[0] += o0[0]; acc[1] += o0[1]; acc[2] += o0[2]; acc[3] += o0[3];
  acc[4] += o1[0]; acc[5] += o1[1]; acc[6] += o1[2]; acc[7] += o1[3];
  f32x4 r0 = {acc[0], acc[1], acc[2], acc[3]};
  f32x4 r1 = {acc[4], acc[5], acc[6], acc[7]};
  __builtin_nontemporal_store(r0, (f32x4*)op);
  __builtin_nontemporal_store(r1, (f32x4*)op + 1);

  float e0 = y0[0]-acc[0], e1 = y0[1]-acc[1], e2 = y0[2]-acc[2], e3 = y0[3]-acc[3];
  float e4 = y1[0]-acc[4], e5 = y1[1]-acc[5], e6 = y1[2]-acc[6], e7 = y1[3]-acc[7];
  float s = e0*e0 + e1*e1 + e2*e2 + e3*e3 + e4*e4 + e5*e5 + e6*e6 + e7*e7;
  #pragma unroll
  for (int off = 32; off > 0; off >>= 1) s += __shfl_down(s, off, 64);
  if ((t & 63) == 0) s_red[t >> 6] = s;
  __syncthreads();
  if (t == 0) atomicAdd(sse, s_red[0] + s_red[1] + s_red[2] + s_red[3]);
}

// Tiny finalize: fvu = sse / (sumsq - sum(colsum^2)/N). Kernel boundary gives visibility.
__global__ __launch_bounds__(256) void fvu_kernel(
    const float* __restrict__ ws, float* __restrict__ fvu_out){
  const int t = threadIdx.x;
  float4 c = ((const float4*)(ws + 4))[t];
  float s = c.x*c.x + c.y*c.y + c.z*c.z + c.w*c.w;
  #pragma unroll
  for (int off = 32; off > 0; off >>= 1) s += __shfl_down(s, off, 64);
  __shared__ float s_red[4];
  if ((t & 63) == 0) s_red[t >> 6] = s;
  __syncthreads();
  if (t == 0){
    float ss = s_red[0] + s_red[1] + s_red[2] + s_red[3];
    float tv = ws[1] - ss / (float)N_TOK;
    fvu_out[0] = ws[0] / tv;
  }
}

extern "C" void kernel_launch(void* const* d_in, const int* in_sizes, int n_in,
                              void* d_out, int out_size, void* d_ws, size_t ws_size,
                              hipStream_t stream){
  const float* x   = (const float*)d_in[0];
  const float* y   = (const float*)d_in[1];
  const float* la  = (const float*)d_in[2];
  const int*   li  = (const int*)d_in[3];
  const float* Wd  = (const float*)d_in[4];
  const float* bd  = (const float*)d_in[5];
  const float* pe  = (const float*)d_in[6];
  const float* pes = (const float*)d_in[7];
  const float* Wsk = (const float*)d_in[8];
  float* out = (float*)d_out;

  float* accs = (float*)d_ws;  // [0]=sse [1]=sumsq [4..1028)=colsum
  unsigned short* xb  = (unsigned short*)((char*)d_ws + 8192);
  unsigned short* wb  = xb + (size_t)N_TOK * DIM;
  unsigned short* wdc = wb + (size_t)DIM * DIM;
  uint2* actbuf = (uint2*)(wdc + (size_t)NCHUNK * NLAT * 128);

  hipMemsetAsync(d_ws, 0, 8192, stream);
  prep<<<5696, 256, 0, stream>>>(x, Wsk, Wd, y, la, li, pe, pes, xb, wb, wdc, actbuf, accs);
  skip_gemm<<<dim3(N_TOK / 128, DIM / 64), 256, 0, stream>>>(xb, wb, bd, out);
  decode_residual<<<(N_TOK / 16) * NCHUNK, 256, 0, stream>>>(y, actbuf, wdc, out, accs);
  fvu_kernel<<<1, 256, 0, stream>>>(accs, out + (size_t)N_TOK * DIM);
}

// Round 5
// 242.071 us; speedup vs baseline: 1.0643x; 1.0643x over previous
//
#include <hip/hip_runtime.h>
#include <hip/hip_bf16.h>
#include <cstdint>

#define N_TOK 4096
#define KTOP  64
#define DIM   1024
#define NLAT  16384
#define NCHUNK 8      // 128 cols/chunk -> 4 MB bf16 per chunk == one XCD L2

typedef __bf16 bf16x8 __attribute__((ext_vector_type(8)));
typedef float  floatx4 __attribute__((ext_vector_type(4)));
typedef float  f32x4   __attribute__((ext_vector_type(4)));
typedef unsigned int   u32x2   __attribute__((ext_vector_type(2)));

#define GLOBAL_AS(p) ((const __attribute__((address_space(1))) void*)(p))
#define LDS_AS(p)    ((__attribute__((address_space(3))) void*)(p))

__device__ inline unsigned short f2bf(float f){
  unsigned int u = __float_as_uint(f);
  unsigned int r = (u + 0x7fffu + ((u >> 16) & 1u)) >> 16;  // RNE
  return (unsigned short)r;
}
__device__ inline float bflo(unsigned int u){ return __uint_as_float(u << 16); }
__device__ inline float bfhi(unsigned int u){ return __uint_as_float(u & 0xffff0000u); }

__device__ inline ushort4 cvt4(float4 v){
  ushort4 o; o.x = f2bf(v.x); o.y = f2bf(v.y); o.z = f2bf(v.z); o.w = f2bf(v.w);
  return o;
}

// Roles (explicit 8-deep load batches -> issue-bound fix; round-4 lesson: cvt8's
// 2-loads-then-dependent-store halved MLP -> 1.38 TB/s. Round-0 pattern, doubled):
//   [0,128)      ystats: colsum + sum(y^2), 32 rows/block in 4-row load groups
//   [128,640)    x->bf16, 8x float4 batch (32 KB/block)
//   [640,768)    Wskip->bf16, same
//   [768,2816)   Wdec->chunked bf16, 8 rows batched (32 KB/block)
//   [2816,2880)  act precompute (register-cheap scalar form)
// accs zeroed by hipMemsetAsync BEFORE this kernel.
__global__ __launch_bounds__(256) void prep(
    const float* __restrict__ x, const float* __restrict__ Wsk,
    const float* __restrict__ Wd, const float* __restrict__ y,
    const float* __restrict__ la, const int* __restrict__ li,
    const float* __restrict__ pe, const float* __restrict__ pes,
    unsigned short* __restrict__ xb, unsigned short* __restrict__ wb,
    unsigned short* __restrict__ wdc,
    uint2* __restrict__ actbuf, float* __restrict__ accs){
  const int b = blockIdx.x;
  const int t = threadIdx.x;
  __shared__ float s_red[4];
  if (b < 128){
    const int r0 = b * 32;
    const float4* y4 = (const float4*)y;
    float4 cs = {0.f, 0.f, 0.f, 0.f};
    float sq = 0.f;
    #pragma unroll
    for (int g = 0; g < 8; g++){
      float4 v0 = y4[(size_t)(r0 + g*4 + 0) * 256 + t];
      float4 v1 = y4[(size_t)(r0 + g*4 + 1) * 256 + t];
      float4 v2 = y4[(size_t)(r0 + g*4 + 2) * 256 + t];
      float4 v3 = y4[(size_t)(r0 + g*4 + 3) * 256 + t];
      cs.x += v0.x + v1.x + v2.x + v3.x;
      cs.y += v0.y + v1.y + v2.y + v3.y;
      cs.z += v0.z + v1.z + v2.z + v3.z;
      cs.w += v0.w + v1.w + v2.w + v3.w;
      sq += v0.x*v0.x + v0.y*v0.y + v0.z*v0.z + v0.w*v0.w;
      sq += v1.x*v1.x + v1.y*v1.y + v1.z*v1.z + v1.w*v1.w;
      sq += v2.x*v2.x + v2.y*v2.y + v2.z*v2.z + v2.w*v2.w;
      sq += v3.x*v3.x + v3.y*v3.y + v3.z*v3.z + v3.w*v3.w;
    }
    atomicAdd(&accs[4 + t*4 + 0], cs.x);
    atomicAdd(&accs[4 + t*4 + 1], cs.y);
    atomicAdd(&accs[4 + t*4 + 2], cs.z);
    atomicAdd(&accs[4 + t*4 + 3], cs.w);
    #pragma unroll
    for (int off = 32; off > 0; off >>= 1) sq += __shfl_down(sq, off, 64);
    if ((t & 63) == 0) s_red[t >> 6] = sq;
    __syncthreads();
    if (t == 0) atomicAdd(&accs[1], s_red[0] + s_red[1] + s_red[2] + s_red[3]);
  } else if (b < 640){
    const float4* xs = (const float4*)x;
    ushort4* xd = (ushort4*)xb;
    const int i0 = (b - 128) * 2048 + t;
    float4 v[8];
    #pragma unroll
    for (int i = 0; i < 8; i++) v[i] = xs[i0 + i * 256];
    #pragma unroll
    for (int i = 0; i < 8; i++) xd[i0 + i * 256] = cvt4(v[i]);
  } else if (b < 768){
    const float4* ws = (const float4*)Wsk;
    ushort4* wd2 = (ushort4*)wb;
    const int i0 = (b - 640) * 2048 + t;
    float4 v[8];
    #pragma unroll
    for (int i = 0; i < 8; i++) v[i] = ws[i0 + i * 256];
    #pragma unroll
    for (int i = 0; i < 8; i++) wd2[i0 + i * 256] = cvt4(v[i]);
  } else if (b < 2816){
    const int r0 = (b - 768) * 8;
    const float4* ws = (const float4*)Wd;
    float4 v[8];
    #pragma unroll
    for (int r = 0; r < 8; r++) v[r] = ws[(size_t)(r0 + r) * 256 + t];
    const int chunk = t >> 5;
    const int off   = (t & 31) * 4;
    #pragma unroll
    for (int r = 0; r < 8; r++)
      *(ushort4*)(wdc + ((size_t)chunk * NLAT + r0 + r) * 128 + off) = cvt4(v[r]);
  } else {
    int e0 = (b - 2816) * 4096 + t;
    #pragma unroll
    for (int i = 0; i < 16; i++){
      int e = e0 + i * 256;
      int id = li[e];
      float a = (la[e] + pe[id]) * pes[id];
      actbuf[e] = make_uint2(__float_as_uint(a), (unsigned)id * 256u);
    }
  }
}

// 128 rows x 64 cols tile -> 512 blocks (2 blocks/CU). m97-style staging. (unchanged)
__global__ __launch_bounds__(256) void skip_gemm(
    const unsigned short* __restrict__ xb,
    const unsigned short* __restrict__ wb,
    const float* __restrict__ b_dec,
    float* __restrict__ out){
  __shared__ unsigned short As[128][32];
  __shared__ unsigned short Bs[64][32];
  const int row0 = blockIdx.x * 128;
  const int col0 = blockIdx.y * 64;
  const int t    = threadIdx.x;
  const int lane = t & 63;
  const int w    = t >> 6;
  const int wr   = w * 32;
  const int lm   = lane & 15;
  const int kq   = lane >> 4;
  const int sr   = t >> 2;
  const int sc   = (t & 3) * 8;

  floatx4 acc[2][4] = {};

  for (int k0 = 0; k0 < DIM; k0 += 32){
    __builtin_amdgcn_global_load_lds(GLOBAL_AS(xb + (size_t)(row0 + sr) * DIM + k0 + sc),
                                     LDS_AS(&As[sr][sc]), 16, 0, 0);
    __builtin_amdgcn_global_load_lds(GLOBAL_AS(xb + (size_t)(row0 + 64 + sr) * DIM + k0 + sc),
                                     LDS_AS(&As[64 + sr][sc]), 16, 0, 0);
    __builtin_amdgcn_global_load_lds(GLOBAL_AS(wb + (size_t)(col0 + sr) * DIM + k0 + sc),
                                     LDS_AS(&Bs[sr][sc]), 16, 0, 0);
    __syncthreads();
    bf16x8 af[2], bfr[4];
    #pragma unroll
    for (int mi = 0; mi < 2; mi++) af[mi] = *(const bf16x8*)(&As[wr + mi * 16 + lm][kq * 8]);
    #pragma unroll
    for (int ni = 0; ni < 4; ni++) bfr[ni] = *(const bf16x8*)(&Bs[ni * 16 + lm][kq * 8]);
    #pragma unroll
    for (int mi = 0; mi < 2; mi++)
      #pragma unroll
      for (int ni = 0; ni < 4; ni++)
        acc[mi][ni] = __builtin_amdgcn_mfma_f32_16x16x32_bf16(af[mi], bfr[ni], acc[mi][ni], 0, 0, 0);
    __syncthreads();
  }

  const int rq = (lane >> 4) * 4;   // C/D: col=lane&15, row=(lane>>4)*4+reg
  #pragma unroll
  for (int mi = 0; mi < 2; mi++){
    #pragma unroll
    for (int ni = 0; ni < 4; ni++){
      int col = col0 + ni * 16 + lm;
      float bd = b_dec[col];
      #pragma unroll
      for (int r = 0; r < 4; r++){
        int row = row0 + wr + mi * 16 + rq + r;
        out[(size_t)row * DIM + col] = acc[mi][ni][r] + bd;
      }
    }
  }
}

// Chunked decode — round-0 structure (compiler-pipelined unroll-16 loop, minimal
// sse-only epilogue) + actbuf precompute + nt streams. No fences (buffer_inv wipes L2).
__global__ __launch_bounds__(256) void decode_residual(
    const float* __restrict__ y,
    const uint2* __restrict__ actbuf,
    const unsigned short* __restrict__ Wdc,  // [NCHUNK][NLAT][128] bf16
    float* __restrict__ out,
    float* __restrict__ sse){
  const int chunk = blockIdx.x & 7;          // == XCD id under round-robin dispatch
  const int tok0  = (blockIdx.x >> 3) * 16;
  const int t  = threadIdx.x;
  const int tl = t >> 4;       // token lane 0..15
  const int cl = t & 15;       // col lane (8 cols each)
  __shared__ uint2 s_ai[16][66];   // stride 66 -> conflict-free
  __shared__ float s_red[4];

  #pragma unroll
  for (int i = 0; i < 4; i++){
    int e = t + i * 256;                 // (tok = e>>6, k = e&63)
    u32x2 v = __builtin_nontemporal_load((const u32x2*)&actbuf[tok0 * KTOP + e]);
    s_ai[e >> 6][e & 63] = make_uint2(v[0], v[1]);
  }
  __syncthreads();
  const int n = tok0 + tl;
  const char* Wbase = (const char*)Wdc + (size_t)chunk * NLAT * 256 + cl * 16;
  float* op = out + (size_t)n * DIM + chunk * 128 + cl * 8;
  const float* yp = y + (size_t)n * DIM + chunk * 128 + cl * 8;
  f32x4 o0 = __builtin_nontemporal_load((const f32x4*)op);
  f32x4 o1 = __builtin_nontemporal_load((const f32x4*)op + 1);
  f32x4 y0 = __builtin_nontemporal_load((const f32x4*)yp);
  f32x4 y1 = __builtin_nontemporal_load((const f32x4*)yp + 1);

  float acc[8] = {};
  #pragma unroll 16
  for (int k = 0; k < KTOP; k++){
    uint2 p = s_ai[tl][k];
    const float a = __uint_as_float(p.x);
    const uint4 wv = *(const uint4*)(Wbase + p.y);
    acc[0] += a * bflo(wv.x); acc[1] += a * bfhi(wv.x);
    acc[2] += a * bflo(wv.y); acc[3] += a * bfhi(wv.y);
    acc[4] += a * bflo(wv.z); acc[5] += a * bfhi(wv.z);
    acc[6] += a * bflo(wv.w); acc[7] += a * bfhi(wv.w);
  }
  acc[0] += o0[0]; acc[1] += o0[1]; acc[2] += o0[2]; acc[3] += o0[3];
  acc[4] += o1[0]; acc[5] += o1[1]; acc[6] += o1[2]; acc[7] += o1[3];
  f32x4 r0 = {acc[0], acc[1], acc[2], acc[3]};
  f32x4 r1 = {acc[4], acc[5], acc[6], acc[7]};
  __builtin_nontemporal_store(r0, (f32x4*)op);
  __builtin_nontemporal_store(r1, (f32x4*)op + 1);

  float e0 = y0[0]-acc[0], e1 = y0[1]-acc[1], e2 = y0[2]-acc[2], e3 = y0[3]-acc[3];
  float e4 = y1[0]-acc[4], e5 = y1[1]-acc[5], e6 = y1[2]-acc[6], e7 = y1[3]-acc[7];
  float s = e0*e0 + e1*e1 + e2*e2 + e3*e3 + e4*e4 + e5*e5 + e6*e6 + e7*e7;
  #pragma unroll
  for (int off = 32; off > 0; off >>= 1) s += __shfl_down(s, off, 64);
  if ((t & 63) == 0) s_red[t >> 6] = s;
  __syncthreads();
  if (t == 0) atomicAdd(sse, s_red[0] + s_red[1] + s_red[2] + s_red[3]);
}

// Tiny finalize: fvu = sse / (sumsq - sum(colsum^2)/N). Kernel boundary gives visibility.
__global__ __launch_bounds__(256) void fvu_kernel(
    const float* __restrict__ ws, float* __restrict__ fvu_out){
  const int t = threadIdx.x;
  float4 c = ((const float4*)(ws + 4))[t];
  float s = c.x*c.x + c.y*c.y + c.z*c.z + c.w*c.w;
  #pragma unroll
  for (int off = 32; off > 0; off >>= 1) s += __shfl_down(s, off, 64);
  __shared__ float s_red[4];
  if ((t & 63) == 0) s_red[t >> 6] = s;
  __syncthreads();
  if (t == 0){
    float ss = s_red[0] + s_red[1] + s_red[2] + s_red[3];
    float tv = ws[1] - ss / (float)N_TOK;
    fvu_out[0] = ws[0] / tv;
  }
}

extern "C" void kernel_launch(void* const* d_in, const int* in_sizes, int n_in,
                              void* d_out, int out_size, void* d_ws, size_t ws_size,
                              hipStream_t stream){
  const float* x   = (const float*)d_in[0];
  const float* y   = (const float*)d_in[1];
  const float* la  = (const float*)d_in[2];
  const int*   li  = (const int*)d_in[3];
  const float* Wd  = (const float*)d_in[4];
  const float* bd  = (const float*)d_in[5];
  const float* pe  = (const float*)d_in[6];
  const float* pes = (const float*)d_in[7];
  const float* Wsk = (const float*)d_in[8];
  float* out = (float*)d_out;

  float* accs = (float*)d_ws;  // [0]=sse [1]=sumsq [4..1028)=colsum
  unsigned short* xb  = (unsigned short*)((char*)d_ws + 8192);
  unsigned short* wb  = xb + (size_t)N_TOK * DIM;
  unsigned short* wdc = wb + (size_t)DIM * DIM;
  uint2* actbuf = (uint2*)(wdc + (size_t)NCHUNK * NLAT * 128);

  hipMemsetAsync(d_ws, 0, 8192, stream);
  prep<<<2880, 256, 0, stream>>>(x, Wsk, Wd, y, la, li, pe, pes, xb, wb, wdc, actbuf, accs);
  skip_gemm<<<dim3(N_TOK / 128, DIM / 64), 256, 0, stream>>>(xb, wb, bd, out);
  decode_residual<<<(N_TOK / 16) * NCHUNK, 256, 0, stream>>>(y, actbuf, wdc, out, accs);
  fvu_kernel<<<1, 256, 0, stream>>>(accs, out + (size_t)N_TOK * DIM);
}